// Round 20
// baseline (50.113 us; speedup 1.0000x reference)
//
#include <hip/hip_runtime.h>
#include <hip/hip_bf16.h>
#include <math.h>

#define N_ROWS 4096
#define D 512
#define TWO_N 8192
#define TILE 128
#define NKT 4                /* 512 / 128 K-steps */
#define NJB 64               /* 8192 / 128 column blocks */
#define NPAIRS 2080          /* 64*65/2 upper-tri blocks */
#define INV_T_EFF 0.01953125f   /* 5/256: acc = 256*sim (z scaled by 16) */

typedef __attribute__((ext_vector_type(4))) int i32x4;
typedef __attribute__((ext_vector_type(8))) int i32x8;
typedef __attribute__((ext_vector_type(4))) float f32x4;
#define AS1 __attribute__((address_space(1)))
#define AS3 __attribute__((address_space(3)))

// ---------------- block reduction helper (broadcasts result) ----------------
template<int K>
__device__ inline void block_reduce_bcast(float (&v)[K]) {
  __shared__ float red[4][K];
  const int t = threadIdx.x;
  #pragma unroll
  for (int off = 32; off; off >>= 1)
    #pragma unroll
    for (int i = 0; i < K; ++i) v[i] += __shfl_xor(v[i], off, 64);
  __syncthreads();
  if ((t & 63) == 0)
    #pragma unroll
    for (int i = 0; i < K; ++i) red[t >> 6][i] = v[i];
  __syncthreads();
  #pragma unroll
  for (int i = 0; i < K; ++i) v[i] = red[0][i] + red[1][i] + red[2][i] + red[3][i];
}

// e2m1 RNE encode of v (|v|<=~6 expected); returns nibble, sets q = decoded
__device__ __forceinline__ int enc_e2m1(float v, float& q) {
  const float a = fabsf(v);
  int idx; float m;
  if (a < 1.75f)      { m = rintf(a * 2.f) * 0.5f; idx = (int)(m * 2.f); }
  else if (a < 3.5f)  { m = rintf(a);              idx = (int)m + 2; }
  else if (a < 5.f)   { m = 4.f;                   idx = 6; }
  else                { m = 6.f;                   idx = 7; }
  if (v < 0.f) { q = -m; return idx | 8; }
  q = m; return idx;
}

// ---------------- kernel 1: wave-per-row normalize -> fp4 e2m1 reps --------
// Stores 16*z quantized to fp4 (2 elems/byte, row = 256B). diagexp computed
// from DEQUANTIZED values so the MFMA diagonal subtraction is exact.
__global__ __launch_bounds__(256) void normalize_kernel(
    const float* __restrict__ ei_, const float* __restrict__ ej_,
    const float* __restrict__ ek_,
    unsigned char* __restrict__ rep4, float* __restrict__ diagexp,
    float* __restrict__ pos_ij, float* __restrict__ exp_ik)
{
  const int t = threadIdx.x;
  const int l = t & 63;
  const int n = blockIdx.x * 4 + (t >> 6);
  const long base = (long)n * D + l * 8;

  float ai[8], aj[8], ak[8];
  #pragma unroll
  for (int h = 0; h < 2; ++h) {
    const float4 vi = *reinterpret_cast<const float4*>(ei_ + base + h * 4);
    const float4 vj = *reinterpret_cast<const float4*>(ej_ + base + h * 4);
    const float4 vk = *reinterpret_cast<const float4*>(ek_ + base + h * 4);
    ai[h*4+0]=vi.x; ai[h*4+1]=vi.y; ai[h*4+2]=vi.z; ai[h*4+3]=vi.w;
    aj[h*4+0]=vj.x; aj[h*4+1]=vj.y; aj[h*4+2]=vj.z; aj[h*4+3]=vj.w;
    ak[h*4+0]=vk.x; ak[h*4+1]=vk.y; ak[h*4+2]=vk.z; ak[h*4+3]=vk.w;
  }

  float v[5] = {0.f, 0.f, 0.f, 0.f, 0.f};
  #pragma unroll
  for (int j = 0; j < 8; ++j) {
    v[0] += ai[j] * ai[j];
    v[1] += aj[j] * aj[j];
    v[2] += ak[j] * ak[j];
    v[3] += ai[j] * aj[j];
    v[4] += ak[j] * ai[j];
  }
  #pragma unroll
  for (int off = 32; off; off >>= 1)
    #pragma unroll
    for (int i = 0; i < 5; ++i) v[i] += __shfl_xor(v[i], off, 64);

  const float ni = fmaxf(sqrtf(v[0]), 1e-12f);
  const float nj = fmaxf(sqrtf(v[1]), 1e-12f);
  const float nk = fmaxf(sqrtf(v[2]), 1e-12f);
  const float invi = 16.0f / ni, invj = 16.0f / nj;   // 16x scale for fp4

  unsigned wi = 0, wj = 0;
  float q[2] = {0.f, 0.f};
  #pragma unroll
  for (int j = 0; j < 8; ++j) {
    float qi, qj;
    wi |= (unsigned)enc_e2m1(ai[j] * invi, qi) << (4 * j);
    wj |= (unsigned)enc_e2m1(aj[j] * invj, qj) << (4 * j);
    q[0] += qi * qi;
    q[1] += qj * qj;
  }
  *reinterpret_cast<unsigned*>(rep4 + (long)n * 256 + l * 4) = wi;
  *reinterpret_cast<unsigned*>(rep4 + (long)(N_ROWS + n) * 256 + l * 4) = wj;

  #pragma unroll
  for (int off = 32; off; off >>= 1)
    #pragma unroll
    for (int i = 0; i < 2; ++i) q[i] += __shfl_xor(q[i], off, 64);

  if (l == 0) {
    diagexp[n]          = __expf(INV_T_EFF * q[0]);   // exp(5*||zq||^2)
    diagexp[N_ROWS + n] = __expf(INV_T_EFF * q[1]);
    pos_ij[n] = v[3] / (ni * nj);                     // exact fp32
    exp_ik[n] = __expf(5.0f * v[4] / (nk * ni));
  }
}

// ---------------- kernel 2: reduce the two scalars --------------------------
__global__ __launch_bounds__(256) void scalar_kernel(
    const float* __restrict__ pos_ij, const float* __restrict__ exp_ik,
    float* __restrict__ scalars)
{
  const int t = threadIdx.x;
  float v[2] = {0.f, 0.f};
  for (int i = t; i < N_ROWS; i += 256) { v[0] += pos_ij[i]; v[1] += exp_ik[i]; }
  block_reduce_bcast<2>(v);
  if (t == 0) { scalars[0] = v[0]; scalars[1] = v[1]; }
}

// ---------------- kernel 3: fp4, FULL-K single-shot stage, ZERO K-barriers --
// fp4 payoff: a full 128-row x K=512 tile = 32KB. Stage ALL of A and B once
// (64KB LDS, 16 gload_lds/thread), ONE syncthreads, then all 64 MFMA/wave
// back-to-back -- the per-K-tile stage->latency->drain->barrier cycle
// (~3.3Kcyc each, the session's dominant cost) is gone. 2 blocks/CU.
// Layout: [row][16 slots of 16B], swizzle slot^(row&15) both-sides
// (per row 4 distinct slots read, <=2-way bank aliasing = free).
__device__ __forceinline__ void stage_full(
    const unsigned char* __restrict__ rep4, char* region, long R0, int t)
{
  #pragma unroll
  for (int s = 0; s < 8; ++s) {
    const int cc = s * 256 + t;          // chunk 0..2047
    const int row = cc >> 4, slot = cc & 15;
    const int sg = slot ^ (row & 15);    // inverse-swizzled source slot
    const unsigned char* g = rep4 + (R0 + row) * 256 + sg * 16;
    __builtin_amdgcn_global_load_lds((const AS1 void*)g,
        (AS3 void*)(region + cc * 16), 16, 0, 0);
  }
}

__global__ __launch_bounds__(256, 2) void gemm_expsum_kernel(
    const unsigned char* __restrict__ rep4, float* __restrict__ S_partial)
{
  __shared__ __align__(16) char smem[65536];   // A 32K | B 32K

  const int t = threadIdx.x;
  const int l = t & 63;
  const int w = t >> 6;          // wave 0..3
  const int wr = w >> 1, wc = w & 1;
  const int s4 = l >> 4;         // k-group 0..3

  // XCD-aware bijective swizzle (2080 = 8*260), then triangular decode I<=J
  const int wg = (blockIdx.x & 7) * 260 + (blockIdx.x >> 3);
  int k = wg, I = 0;
  while (k >= NJB - I) { k -= NJB - I; ++I; }
  const int J = I + k;
  const long rI = (long)I * TILE;
  const long cJ = (long)J * TILE;

  // row byte-bases; per-K-step slot is ((kt*4+s4)^(l&15))*16, shared A/B
  int a_row[4], b_row[4];
  #pragma unroll
  for (int mi = 0; mi < 4; ++mi)
    a_row[mi] = (wr * 64 + mi * 16 + (l & 15)) * 256;
  #pragma unroll
  for (int ni = 0; ni < 4; ++ni)
    b_row[ni] = 32768 + (wc * 64 + ni * 16 + (l & 15)) * 256;

  f32x4 acc[4][4];
  #pragma unroll
  for (int a = 0; a < 4; ++a)
    #pragma unroll
    for (int b = 0; b < 4; ++b) { f32x4 z = {0.f, 0.f, 0.f, 0.f}; acc[a][b] = z; }

  // single-shot stage of both full tiles; syncthreads drains vmcnt
  stage_full(rep4, smem, rI, t);
  stage_full(rep4, smem + 32768, cJ, t);
  __syncthreads();

  const i32x4 zero4 = {0, 0, 0, 0};
  #pragma unroll
  for (int kt = 0; kt < NKT; ++kt) {
    const int sl = (((kt * 4 + s4) ^ (l & 15)) << 4);
    i32x8 bf[4];
    #pragma unroll
    for (int ni = 0; ni < 4; ++ni) {
      const i32x4 lo = *reinterpret_cast<const i32x4*>(smem + b_row[ni] + sl);
      bf[ni] = __builtin_shufflevector(lo, zero4, 0, 1, 2, 3, 4, 5, 6, 7);
    }
    #pragma unroll
    for (int mi = 0; mi < 4; ++mi) {
      const i32x4 lo = *reinterpret_cast<const i32x4*>(smem + a_row[mi] + sl);
      const i32x8 af = __builtin_shufflevector(lo, zero4, 0, 1, 2, 3, 4, 5, 6, 7);
      #pragma unroll
      for (int ni = 0; ni < 4; ++ni)
        acc[mi][ni] = __builtin_amdgcn_mfma_scale_f32_16x16x128_f8f6f4(
            af, bf[ni], acc[mi][ni], 4 /*A fmt fp4*/, 4 /*B fmt fp4*/,
            0, 0x7F7F7F7F, 0, 0x7F7F7F7F);
    }
  }
  __syncthreads();                       // all ds_reads retired: smem reusable
  float* rowbuf = (float*)smem;          // [2][128]
  float* colbuf = (float*)(smem + 1024); // [2][128]

  // epilogue: e = exp((5/256)*acc); row-sums + col-sums (symmetry)
  // C/D layout shape-determined: col=l&15, row=(l>>4)*4+j
  float rsum[4][4], csum[4];
  #pragma unroll
  for (int mi = 0; mi < 4; ++mi)
    #pragma unroll
    for (int j = 0; j < 4; ++j) rsum[mi][j] = 0.f;
  #pragma unroll
  for (int ni = 0; ni < 4; ++ni) csum[ni] = 0.f;

  #pragma unroll
  for (int mi = 0; mi < 4; ++mi)
    #pragma unroll
    for (int ni = 0; ni < 4; ++ni)
      #pragma unroll
      for (int j = 0; j < 4; ++j) {
        const float e = __expf(INV_T_EFF * acc[mi][ni][j]);
        rsum[mi][j] += e;
        csum[ni]    += e;
      }

  #pragma unroll
  for (int mi = 0; mi < 4; ++mi) {
    #pragma unroll
    for (int off = 1; off < 16; off <<= 1)
      #pragma unroll
      for (int j = 0; j < 4; ++j) rsum[mi][j] += __shfl_xor(rsum[mi][j], off, 64);
    if ((l & 15) == 0) {
      const int rloc = wr * 64 + mi * 16 + s4 * 4;
      #pragma unroll
      for (int j = 0; j < 4; ++j) rowbuf[wc * TILE + rloc + j] = rsum[mi][j];
    }
  }
  #pragma unroll
  for (int off = 16; off < 64; off <<= 1)
    #pragma unroll
    for (int ni = 0; ni < 4; ++ni) csum[ni] += __shfl_xor(csum[ni], off, 64);
  if (l < 16) {
    #pragma unroll
    for (int ni = 0; ni < 4; ++ni)
      colbuf[wr * TILE + wc * 64 + ni * 16 + l] = csum[ni];
  }
  __syncthreads();

  if (t < TILE) {
    S_partial[(long)J * TWO_N + rI + t] = rowbuf[t] + rowbuf[TILE + t];
  } else if (I != J) {
    const int c = t - TILE;
    S_partial[(long)I * TWO_N + cJ + c] = colbuf[c] + colbuf[TILE + c];
  }
}

// ---------------- kernel 4: per-row log(denominator), block partials -------
__global__ __launch_bounds__(256) void rowlog_kernel(
    const float* __restrict__ S_partial, const float* __restrict__ diagexp,
    const float* __restrict__ scalars, float* __restrict__ blockpart)
{
  const int t = threadIdx.x;
  const int r = blockIdx.x * 256 + t;
  float s = 0.f;
  #pragma unroll 8
  for (int Jb = 0; Jb < NJB; ++Jb) s += S_partial[(long)Jb * TWO_N + r];
  const float denom_fu = 2.0f * scalars[1];
  float v[1];
  v[0] = logf(s - diagexp[r] + denom_fu);
  block_reduce_bcast<1>(v);
  if (t == 0) blockpart[blockIdx.x] = v[0];
}

// ---------------- kernel 5: final scalar -----------------------------------
__global__ void final_kernel(const float* __restrict__ blockpart,
                             const float* __restrict__ scalars,
                             float* __restrict__ out)
{
  const int t = threadIdx.x;   // 64 threads
  float s = (t < TWO_N / 256) ? blockpart[t] : 0.f;
  #pragma unroll
  for (int off = 32; off; off >>= 1) s += __shfl_xor(s, off, 64);
  if (t == 0) out[0] = (s - 10.0f * scalars[0]) / (float)TWO_N;
}

extern "C" void kernel_launch(void* const* d_in, const int* in_sizes, int n_in,
                              void* d_out, int out_size, void* d_ws, size_t ws_size,
                              hipStream_t stream)
{
  const float* ei = (const float*)d_in[0];
  const float* ej = (const float*)d_in[1];
  const float* ek = (const float*)d_in[2];
  float* out = (float*)d_out;

  char* ws = (char*)d_ws;
  unsigned char* rep4 = (unsigned char*)ws;                            // 2 MB
  float* S_partial = (float*)(ws + 2u * 1024 * 1024);                  // 2 MB
  float* diagexp   = (float*)(ws + 4u * 1024 * 1024);                  // 32 KB
  float* pos_ij    = (float*)(ws + 4u * 1024 * 1024 + 32 * 1024);      // 16 KB
  float* exp_ik    = (float*)(ws + 4u * 1024 * 1024 + 48 * 1024);      // 16 KB
  float* scalars   = (float*)(ws + 4u * 1024 * 1024 + 64 * 1024);      // 8 B
  float* blockpart = (float*)(ws + 4u * 1024 * 1024 + 64 * 1024 + 256); // 128 B

  normalize_kernel<<<N_ROWS / 4, 256, 0, stream>>>(ei, ej, ek, rep4, diagexp,
                                                   pos_ij, exp_ik);
  scalar_kernel<<<1, 256, 0, stream>>>(pos_ij, exp_ik, scalars);
  gemm_expsum_kernel<<<NPAIRS, 256, 0, stream>>>(rep4, S_partial);
  rowlog_kernel<<<TWO_N / 256, 256, 0, stream>>>(S_partial, diagexp, scalars,
                                                 blockpart);
  final_kernel<<<1, 64, 0, stream>>>(blockpart, scalars, out);
}

// Round 21
// 43.018 us; speedup vs baseline: 1.1649x; 1.1649x over previous
//
#include <hip/hip_runtime.h>
#include <hip/hip_bf16.h>
#include <math.h>

#define N_ROWS 4096
#define D 512
#define TWO_N 8192
#define TILE 128
#define NKT 4                /* 512 / 128 K-tiles */
#define NJB 64               /* 8192 / 128 column blocks */
#define NPAIRS 2080          /* 64*65/2 upper-tri blocks */
#define INV_T_EFF 0.01953125f   /* 5/256: acc = 256*sim (z scaled by 16) */

typedef __attribute__((ext_vector_type(4))) int i32x4;
typedef __attribute__((ext_vector_type(8))) int i32x8;
typedef __attribute__((ext_vector_type(4))) float f32x4;
#define AS1 __attribute__((address_space(1)))
#define AS3 __attribute__((address_space(3)))

// ---------------- block reduction helper (broadcasts result) ----------------
template<int K>
__device__ inline void block_reduce_bcast(float (&v)[K]) {
  __shared__ float red[4][K];
  const int t = threadIdx.x;
  #pragma unroll
  for (int off = 32; off; off >>= 1)
    #pragma unroll
    for (int i = 0; i < K; ++i) v[i] += __shfl_xor(v[i], off, 64);
  __syncthreads();
  if ((t & 63) == 0)
    #pragma unroll
    for (int i = 0; i < K; ++i) red[t >> 6][i] = v[i];
  __syncthreads();
  #pragma unroll
  for (int i = 0; i < K; ++i) v[i] = red[0][i] + red[1][i] + red[2][i] + red[3][i];
}

// e2m1 RNE encode of v (|v|<=~6 expected); returns nibble, sets q = decoded
__device__ __forceinline__ int enc_e2m1(float v, float& q) {
  const float a = fabsf(v);
  int idx; float m;
  if (a < 1.75f)      { m = rintf(a * 2.f) * 0.5f; idx = (int)(m * 2.f); }
  else if (a < 3.5f)  { m = rintf(a);              idx = (int)m + 2; }
  else if (a < 5.f)   { m = 4.f;                   idx = 6; }
  else                { m = 6.f;                   idx = 7; }
  if (v < 0.f) { q = -m; return idx | 8; }
  q = m; return idx;
}

// ---------------- kernel 1: wave-per-row normalize -> fp4 e2m1 reps --------
// Stores 16*z quantized to fp4 (2 elems/byte, row = 256B). diagexp computed
// from DEQUANTIZED values so the MFMA diagonal subtraction is exact.
__global__ __launch_bounds__(256) void normalize_kernel(
    const float* __restrict__ ei_, const float* __restrict__ ej_,
    const float* __restrict__ ek_,
    unsigned char* __restrict__ rep4, float* __restrict__ diagexp,
    float* __restrict__ pos_ij, float* __restrict__ exp_ik)
{
  const int t = threadIdx.x;
  const int l = t & 63;
  const int n = blockIdx.x * 4 + (t >> 6);
  const long base = (long)n * D + l * 8;

  float ai[8], aj[8], ak[8];
  #pragma unroll
  for (int h = 0; h < 2; ++h) {
    const float4 vi = *reinterpret_cast<const float4*>(ei_ + base + h * 4);
    const float4 vj = *reinterpret_cast<const float4*>(ej_ + base + h * 4);
    const float4 vk = *reinterpret_cast<const float4*>(ek_ + base + h * 4);
    ai[h*4+0]=vi.x; ai[h*4+1]=vi.y; ai[h*4+2]=vi.z; ai[h*4+3]=vi.w;
    aj[h*4+0]=vj.x; aj[h*4+1]=vj.y; aj[h*4+2]=vj.z; aj[h*4+3]=vj.w;
    ak[h*4+0]=vk.x; ak[h*4+1]=vk.y; ak[h*4+2]=vk.z; ak[h*4+3]=vk.w;
  }

  float v[5] = {0.f, 0.f, 0.f, 0.f, 0.f};
  #pragma unroll
  for (int j = 0; j < 8; ++j) {
    v[0] += ai[j] * ai[j];
    v[1] += aj[j] * aj[j];
    v[2] += ak[j] * ak[j];
    v[3] += ai[j] * aj[j];
    v[4] += ak[j] * ai[j];
  }
  #pragma unroll
  for (int off = 32; off; off >>= 1)
    #pragma unroll
    for (int i = 0; i < 5; ++i) v[i] += __shfl_xor(v[i], off, 64);

  const float ni = fmaxf(sqrtf(v[0]), 1e-12f);
  const float nj = fmaxf(sqrtf(v[1]), 1e-12f);
  const float nk = fmaxf(sqrtf(v[2]), 1e-12f);
  const float invi = 16.0f / ni, invj = 16.0f / nj;   // 16x scale for fp4

  unsigned wi = 0, wj = 0;
  float q[2] = {0.f, 0.f};
  #pragma unroll
  for (int j = 0; j < 8; ++j) {
    float qi, qj;
    wi |= (unsigned)enc_e2m1(ai[j] * invi, qi) << (4 * j);
    wj |= (unsigned)enc_e2m1(aj[j] * invj, qj) << (4 * j);
    q[0] += qi * qi;
    q[1] += qj * qj;
  }
  *reinterpret_cast<unsigned*>(rep4 + (long)n * 256 + l * 4) = wi;
  *reinterpret_cast<unsigned*>(rep4 + (long)(N_ROWS + n) * 256 + l * 4) = wj;

  #pragma unroll
  for (int off = 32; off; off >>= 1)
    #pragma unroll
    for (int i = 0; i < 2; ++i) q[i] += __shfl_xor(q[i], off, 64);

  if (l == 0) {
    diagexp[n]          = __expf(INV_T_EFF * q[0]);   // exp(5*||zq||^2)
    diagexp[N_ROWS + n] = __expf(INV_T_EFF * q[1]);
    pos_ij[n] = v[3] / (ni * nj);                     // exact fp32
    exp_ik[n] = __expf(5.0f * v[4] / (nk * ni));
  }
}

// ---------------- kernel 2: 128^2 MX-fp4 K=128 GEMM + exp + sums -----------
// R19 champion structure, unchanged. FMT=4 (fp4): staged bytes half of fp8,
// fp4 matrix rate 1.55x. A and B staged identically -> k-permutation cancels.
// Row = 64B = 4 slots of 16B; swizzle slot^((row>>1)&3) (2 lanes/bank=free);
// inverse swizzle on global source. Unit e8m0 scales (0x7F = 2^0).
__device__ __forceinline__ void stage4(
    const unsigned char* __restrict__ rep4, char* region,
    long R0, int kt, int t)
{
  #pragma unroll
  for (int s = 0; s < 2; ++s) {
    const int cc = s * 256 + t;          // chunk 0..511
    const int row = cc >> 2, slot = cc & 3;
    const int sg = slot ^ ((row >> 1) & 3);   // inverse-swizzled source slot
    const unsigned char* g = rep4 + (R0 + row) * 256 + kt * 64 + sg * 16;
    __builtin_amdgcn_global_load_lds((const AS1 void*)g,
        (AS3 void*)(region + cc * 16), 16, 0, 0);
  }
}

__global__ __launch_bounds__(256, 2) void gemm_expsum_kernel(
    const unsigned char* __restrict__ rep4, float* __restrict__ S_partial)
{
  __shared__ __align__(16) char smem[16384];   // A 8K | B 8K

  const int t = threadIdx.x;
  const int l = t & 63;
  const int w = t >> 6;          // wave 0..3
  const int wr = w >> 1, wc = w & 1;
  const int s4 = l >> 4;         // k-group 0..3

  // XCD-aware bijective swizzle (2080 = 8*260), then triangular decode I<=J
  const int wg = (blockIdx.x & 7) * 260 + (blockIdx.x >> 3);
  int k = wg, I = 0;
  while (k >= NJB - I) { k -= NJB - I; ++I; }
  const int J = I + k;
  const long rI = (long)I * TILE;
  const long cJ = (long)J * TILE;

  // fragment byte offsets: row*64 + swizzled 16B slot ((row>>1)&3 == (l>>1)&3)
  const int swz16 = ((s4 ^ ((l >> 1) & 3)) << 4);
  int a_off[4], b_off[4];
  #pragma unroll
  for (int mi = 0; mi < 4; ++mi)
    a_off[mi] = (wr * 64 + mi * 16 + (l & 15)) * 64 + swz16;
  #pragma unroll
  for (int ni = 0; ni < 4; ++ni)
    b_off[ni] = 8192 + (wc * 64 + ni * 16 + (l & 15)) * 64 + swz16;

  f32x4 acc[4][4];
  #pragma unroll
  for (int a = 0; a < 4; ++a)
    #pragma unroll
    for (int b = 0; b < 4; ++b) { f32x4 z = {0.f, 0.f, 0.f, 0.f}; acc[a][b] = z; }

  const i32x4 zero4 = {0, 0, 0, 0};

  for (int kt = 0; kt < NKT; ++kt) {
    if (kt) __syncthreads();             // everyone done reading prev tile
    stage4(rep4, smem, rI, kt, t);
    stage4(rep4, smem + 8192, cJ, kt, t);
    __syncthreads();                     // drains vmcnt(0): tile landed

    i32x8 bf[4];
    #pragma unroll
    for (int ni = 0; ni < 4; ++ni) {
      const i32x4 lo = *reinterpret_cast<const i32x4*>(smem + b_off[ni]);
      bf[ni] = __builtin_shufflevector(lo, zero4, 0, 1, 2, 3, 4, 5, 6, 7);
    }
    __builtin_amdgcn_s_setprio(1);
    #pragma unroll
    for (int mi = 0; mi < 4; ++mi) {
      const i32x4 lo = *reinterpret_cast<const i32x4*>(smem + a_off[mi]);
      const i32x8 af = __builtin_shufflevector(lo, zero4, 0, 1, 2, 3, 4, 5, 6, 7);
      #pragma unroll
      for (int ni = 0; ni < 4; ++ni)
        acc[mi][ni] = __builtin_amdgcn_mfma_scale_f32_16x16x128_f8f6f4(
            af, bf[ni], acc[mi][ni], 4 /*A fmt fp4*/, 4 /*B fmt fp4*/,
            0, 0x7F7F7F7F, 0, 0x7F7F7F7F);
    }
    __builtin_amdgcn_s_setprio(0);
  }
  __syncthreads();                       // all ds_reads retired: smem reusable
  float* rowbuf = (float*)smem;          // [2][128]
  float* colbuf = (float*)(smem + 1024); // [2][128]

  // epilogue: e = exp((5/256)*acc); row-sums + col-sums (symmetry)
  // C/D layout shape-determined: col=l&15, row=(l>>4)*4+j
  float rsum[4][4], csum[4];
  #pragma unroll
  for (int mi = 0; mi < 4; ++mi)
    #pragma unroll
    for (int j = 0; j < 4; ++j) rsum[mi][j] = 0.f;
  #pragma unroll
  for (int ni = 0; ni < 4; ++ni) csum[ni] = 0.f;

  #pragma unroll
  for (int mi = 0; mi < 4; ++mi)
    #pragma unroll
    for (int ni = 0; ni < 4; ++ni)
      #pragma unroll
      for (int j = 0; j < 4; ++j) {
        const float e = __expf(INV_T_EFF * acc[mi][ni][j]);
        rsum[mi][j] += e;
        csum[ni]    += e;
      }

  #pragma unroll
  for (int mi = 0; mi < 4; ++mi) {
    #pragma unroll
    for (int off = 1; off < 16; off <<= 1)
      #pragma unroll
      for (int j = 0; j < 4; ++j) rsum[mi][j] += __shfl_xor(rsum[mi][j], off, 64);
    if ((l & 15) == 0) {
      const int rloc = wr * 64 + mi * 16 + s4 * 4;
      #pragma unroll
      for (int j = 0; j < 4; ++j) rowbuf[wc * TILE + rloc + j] = rsum[mi][j];
    }
  }
  #pragma unroll
  for (int off = 16; off < 64; off <<= 1)
    #pragma unroll
    for (int ni = 0; ni < 4; ++ni) csum[ni] += __shfl_xor(csum[ni], off, 64);
  if (l < 16) {
    #pragma unroll
    for (int ni = 0; ni < 4; ++ni)
      colbuf[wr * TILE + wc * 64 + ni * 16 + l] = csum[ni];
  }
  __syncthreads();

  if (t < TILE) {
    S_partial[(long)J * TWO_N + rI + t] = rowbuf[t] + rowbuf[TILE + t];
  } else if (I != J) {
    const int c = t - TILE;
    S_partial[(long)I * TWO_N + cJ + c] = colbuf[c] + colbuf[TILE + c];
  }
}

// ---------------- kernel 3: per-row log(denominator) + inline exp_ik sum ---
// scalar_kernel eliminated: each block redundantly sums exp_ik (4096 floats,
// identical deterministic order per block -> identical value).
__global__ __launch_bounds__(256) void rowlog_kernel(
    const float* __restrict__ S_partial, const float* __restrict__ diagexp,
    const float* __restrict__ exp_ik, float* __restrict__ blockpart)
{
  const int t = threadIdx.x;
  const int r = blockIdx.x * 256 + t;

  float fu[1] = {0.f};
  #pragma unroll 4
  for (int i = t; i < N_ROWS; i += 256) fu[0] += exp_ik[i];
  block_reduce_bcast<1>(fu);
  const float denom_fu = 2.0f * fu[0];

  float s = 0.f;
  #pragma unroll 8
  for (int Jb = 0; Jb < NJB; ++Jb) s += S_partial[(long)Jb * TWO_N + r];
  float v[1];
  v[0] = logf(s - diagexp[r] + denom_fu);
  block_reduce_bcast<1>(v);
  if (t == 0) blockpart[blockIdx.x] = v[0];
}

// ---------------- kernel 4: final scalar (+ inline pos_ij sum) -------------
__global__ __launch_bounds__(256) void final_kernel(
    const float* __restrict__ blockpart, const float* __restrict__ pos_ij,
    float* __restrict__ out)
{
  const int t = threadIdx.x;   // 256 threads
  float v[2] = {0.f, 0.f};
  #pragma unroll 4
  for (int i = t; i < N_ROWS; i += 256) v[0] += pos_ij[i];
  if (t < TWO_N / 256) v[1] = blockpart[t];
  block_reduce_bcast<2>(v);
  if (t == 0) out[0] = (v[1] - 10.0f * v[0]) / (float)TWO_N;
}

extern "C" void kernel_launch(void* const* d_in, const int* in_sizes, int n_in,
                              void* d_out, int out_size, void* d_ws, size_t ws_size,
                              hipStream_t stream)
{
  const float* ei = (const float*)d_in[0];
  const float* ej = (const float*)d_in[1];
  const float* ek = (const float*)d_in[2];
  float* out = (float*)d_out;

  char* ws = (char*)d_ws;
  unsigned char* rep4 = (unsigned char*)ws;                            // 2 MB
  float* S_partial = (float*)(ws + 2u * 1024 * 1024);                  // 2 MB
  float* diagexp   = (float*)(ws + 4u * 1024 * 1024);                  // 32 KB
  float* pos_ij    = (float*)(ws + 4u * 1024 * 1024 + 32 * 1024);      // 16 KB
  float* exp_ik    = (float*)(ws + 4u * 1024 * 1024 + 48 * 1024);      // 16 KB
  float* blockpart = (float*)(ws + 4u * 1024 * 1024 + 64 * 1024);      // 128 B

  normalize_kernel<<<N_ROWS / 4, 256, 0, stream>>>(ei, ej, ek, rep4, diagexp,
                                                   pos_ij, exp_ik);
  gemm_expsum_kernel<<<NPAIRS, 256, 0, stream>>>(rep4, S_partial);
  rowlog_kernel<<<TWO_N / 256, 256, 0, stream>>>(S_partial, diagexp, exp_ik,
                                                 blockpart);
  final_kernel<<<1, 256, 0, stream>>>(blockpart, pos_ij, out);
}

// Round 22
// 42.364 us; speedup vs baseline: 1.1829x; 1.0154x over previous
//
#include <hip/hip_runtime.h>
#include <hip/hip_bf16.h>
#include <math.h>

#define N_ROWS 4096
#define D 512
#define TWO_N 8192
#define TILE 128
#define NKT 4                /* 512 / 128 K-tiles */
#define NJB 64               /* 8192 / 128 column blocks */
#define NPAIRS 2080          /* 64*65/2 upper-tri blocks */
#define INV_T_EFF 0.01953125f   /* 5/256: acc = 256*sim (z scaled by 16) */

typedef __attribute__((ext_vector_type(4))) int i32x4;
typedef __attribute__((ext_vector_type(8))) int i32x8;
typedef __attribute__((ext_vector_type(4))) float f32x4;
#define AS1 __attribute__((address_space(1)))
#define AS3 __attribute__((address_space(3)))

// ---------------- block reduction helper (broadcasts result) ----------------
template<int K>
__device__ inline void block_reduce_bcast(float (&v)[K]) {
  __shared__ float red[4][K];
  const int t = threadIdx.x;
  #pragma unroll
  for (int off = 32; off; off >>= 1)
    #pragma unroll
    for (int i = 0; i < K; ++i) v[i] += __shfl_xor(v[i], off, 64);
  __syncthreads();
  if ((t & 63) == 0)
    #pragma unroll
    for (int i = 0; i < K; ++i) red[t >> 6][i] = v[i];
  __syncthreads();
  #pragma unroll
  for (int i = 0; i < K; ++i) v[i] = red[0][i] + red[1][i] + red[2][i] + red[3][i];
}

// e2m1 RNE encode of v (|v|<=~6 expected); returns nibble, sets q = decoded
__device__ __forceinline__ int enc_e2m1(float v, float& q) {
  const float a = fabsf(v);
  int idx; float m;
  if (a < 1.75f)      { m = rintf(a * 2.f) * 0.5f; idx = (int)(m * 2.f); }
  else if (a < 3.5f)  { m = rintf(a);              idx = (int)m + 2; }
  else if (a < 5.f)   { m = 4.f;                   idx = 6; }
  else                { m = 6.f;                   idx = 7; }
  if (v < 0.f) { q = -m; return idx | 8; }
  q = m; return idx;
}

// ---------------- kernel 1: wave-per-row normalize -> fp4 e2m1 reps --------
__global__ __launch_bounds__(256) void normalize_kernel(
    const float* __restrict__ ei_, const float* __restrict__ ej_,
    const float* __restrict__ ek_,
    unsigned char* __restrict__ rep4, float* __restrict__ diagexp,
    float* __restrict__ pos_ij, float* __restrict__ exp_ik)
{
  const int t = threadIdx.x;
  const int l = t & 63;
  const int n = blockIdx.x * 4 + (t >> 6);
  const long base = (long)n * D + l * 8;

  float ai[8], aj[8], ak[8];
  #pragma unroll
  for (int h = 0; h < 2; ++h) {
    const float4 vi = *reinterpret_cast<const float4*>(ei_ + base + h * 4);
    const float4 vj = *reinterpret_cast<const float4*>(ej_ + base + h * 4);
    const float4 vk = *reinterpret_cast<const float4*>(ek_ + base + h * 4);
    ai[h*4+0]=vi.x; ai[h*4+1]=vi.y; ai[h*4+2]=vi.z; ai[h*4+3]=vi.w;
    aj[h*4+0]=vj.x; aj[h*4+1]=vj.y; aj[h*4+2]=vj.z; aj[h*4+3]=vj.w;
    ak[h*4+0]=vk.x; ak[h*4+1]=vk.y; ak[h*4+2]=vk.z; ak[h*4+3]=vk.w;
  }

  float v[5] = {0.f, 0.f, 0.f, 0.f, 0.f};
  #pragma unroll
  for (int j = 0; j < 8; ++j) {
    v[0] += ai[j] * ai[j];
    v[1] += aj[j] * aj[j];
    v[2] += ak[j] * ak[j];
    v[3] += ai[j] * aj[j];
    v[4] += ak[j] * ai[j];
  }
  #pragma unroll
  for (int off = 32; off; off >>= 1)
    #pragma unroll
    for (int i = 0; i < 5; ++i) v[i] += __shfl_xor(v[i], off, 64);

  const float ni = fmaxf(sqrtf(v[0]), 1e-12f);
  const float nj = fmaxf(sqrtf(v[1]), 1e-12f);
  const float nk = fmaxf(sqrtf(v[2]), 1e-12f);
  const float invi = 16.0f / ni, invj = 16.0f / nj;   // 16x scale for fp4

  unsigned wi = 0, wj = 0;
  float q[2] = {0.f, 0.f};
  #pragma unroll
  for (int j = 0; j < 8; ++j) {
    float qi, qj;
    wi |= (unsigned)enc_e2m1(ai[j] * invi, qi) << (4 * j);
    wj |= (unsigned)enc_e2m1(aj[j] * invj, qj) << (4 * j);
    q[0] += qi * qi;
    q[1] += qj * qj;
  }
  *reinterpret_cast<unsigned*>(rep4 + (long)n * 256 + l * 4) = wi;
  *reinterpret_cast<unsigned*>(rep4 + (long)(N_ROWS + n) * 256 + l * 4) = wj;

  #pragma unroll
  for (int off = 32; off; off >>= 1)
    #pragma unroll
    for (int i = 0; i < 2; ++i) q[i] += __shfl_xor(q[i], off, 64);

  if (l == 0) {
    diagexp[n]          = __expf(INV_T_EFF * q[0]);   // exp(5*||zq||^2)
    diagexp[N_ROWS + n] = __expf(INV_T_EFF * q[1]);
    pos_ij[n] = v[3] / (ni * nj);                     // exact fp32
    exp_ik[n] = __expf(5.0f * v[4] / (nk * ni));
  }
}

// ---------------- kernel 2: fp4 K=128 GEMM, stage-ahead dbuf (R8 recipe) ---
// R8's proven schedule at fp4's LDS scale: stage T(k+1) into buf p^1 BEFORE
// compute(k); ONE syncthreads per K-tile (drain hides under MFMA). dbuf =
// 2 x 16KB = 32KB -> up to 5 blocks/CU (R8's regime; R13's fp8-dbuf null was
// at 2 blocks/CU). Hazard ledger (R8/R11-proven): iter-k barrier retires all
// reads of buf p before iter k+1 re-stages it; the same barrier's vmcnt-drain
// publishes tile k+1. Row = 64B = 4 slots of 16B; swizzle slot^((row>>1)&3);
// inverse swizzle on global source. Unit e8m0 scales (0x7F = 2^0).
__device__ __forceinline__ void stage4(
    const unsigned char* __restrict__ rep4, char* region,
    long R0, int kt, int t)
{
  #pragma unroll
  for (int s = 0; s < 2; ++s) {
    const int cc = s * 256 + t;          // chunk 0..511
    const int row = cc >> 2, slot = cc & 3;
    const int sg = slot ^ ((row >> 1) & 3);   // inverse-swizzled source slot
    const unsigned char* g = rep4 + (R0 + row) * 256 + kt * 64 + sg * 16;
    __builtin_amdgcn_global_load_lds((const AS1 void*)g,
        (AS3 void*)(region + cc * 16), 16, 0, 0);
  }
}

__global__ __launch_bounds__(256, 2) void gemm_expsum_kernel(
    const unsigned char* __restrict__ rep4, float* __restrict__ S_partial)
{
  __shared__ __align__(16) char smem[32768];   // [p][A 8K | B 8K]

  const int t = threadIdx.x;
  const int l = t & 63;
  const int w = t >> 6;          // wave 0..3
  const int wr = w >> 1, wc = w & 1;
  const int s4 = l >> 4;         // k-group 0..3

  // XCD-aware bijective swizzle (2080 = 8*260), then triangular decode I<=J
  const int wg = (blockIdx.x & 7) * 260 + (blockIdx.x >> 3);
  int k = wg, I = 0;
  while (k >= NJB - I) { k -= NJB - I; ++I; }
  const int J = I + k;
  const long rI = (long)I * TILE;
  const long cJ = (long)J * TILE;

  // fragment byte offsets within a buffer: row*64 + swizzled 16B slot
  const int swz16 = ((s4 ^ ((l >> 1) & 3)) << 4);
  int a_off[4], b_off[4];
  #pragma unroll
  for (int mi = 0; mi < 4; ++mi)
    a_off[mi] = (wr * 64 + mi * 16 + (l & 15)) * 64 + swz16;
  #pragma unroll
  for (int ni = 0; ni < 4; ++ni)
    b_off[ni] = 8192 + (wc * 64 + ni * 16 + (l & 15)) * 64 + swz16;

  f32x4 acc[4][4];
  #pragma unroll
  for (int a = 0; a < 4; ++a)
    #pragma unroll
    for (int b = 0; b < 4; ++b) { f32x4 z = {0.f, 0.f, 0.f, 0.f}; acc[a][b] = z; }

  const i32x4 zero4 = {0, 0, 0, 0};

  // prologue: stage T0 into buf0; syncthreads drains vmcnt
  stage4(rep4, smem, rI, 0, t);
  stage4(rep4, smem + 8192, cJ, 0, t);
  __syncthreads();

  for (int kt = 0; kt < NKT; ++kt) {
    const int p = kt & 1;
    char* cur = smem + p * 16384;
    if (kt < NKT - 1) {                  // issue next tile BEFORE compute
      char* nxt = smem + (p ^ 1) * 16384;
      stage4(rep4, nxt, rI, kt + 1, t);
      stage4(rep4, nxt + 8192, cJ, kt + 1, t);
    }
    i32x8 bf[4];
    #pragma unroll
    for (int ni = 0; ni < 4; ++ni) {
      const i32x4 lo = *reinterpret_cast<const i32x4*>(cur + b_off[ni]);
      bf[ni] = __builtin_shufflevector(lo, zero4, 0, 1, 2, 3, 4, 5, 6, 7);
    }
    __builtin_amdgcn_s_setprio(1);
    #pragma unroll
    for (int mi = 0; mi < 4; ++mi) {
      const i32x4 lo = *reinterpret_cast<const i32x4*>(cur + a_off[mi]);
      const i32x8 af = __builtin_shufflevector(lo, zero4, 0, 1, 2, 3, 4, 5, 6, 7);
      #pragma unroll
      for (int ni = 0; ni < 4; ++ni)
        acc[mi][ni] = __builtin_amdgcn_mfma_scale_f32_16x16x128_f8f6f4(
            af, bf[ni], acc[mi][ni], 4 /*A fmt fp4*/, 4 /*B fmt fp4*/,
            0, 0x7F7F7F7F, 0, 0x7F7F7F7F);
    }
    __builtin_amdgcn_s_setprio(0);
    __syncthreads();   // drains vmcnt(0): T(k+1) landed; all reads of p done
  }
  float* rowbuf = (float*)smem;          // [2][128] (smem dead after barrier)
  float* colbuf = (float*)(smem + 1024); // [2][128]

  // epilogue: e = exp((5/256)*acc); row-sums + col-sums (symmetry)
  // C/D layout shape-determined: col=l&15, row=(l>>4)*4+j
  float rsum[4][4], csum[4];
  #pragma unroll
  for (int mi = 0; mi < 4; ++mi)
    #pragma unroll
    for (int j = 0; j < 4; ++j) rsum[mi][j] = 0.f;
  #pragma unroll
  for (int ni = 0; ni < 4; ++ni) csum[ni] = 0.f;

  #pragma unroll
  for (int mi = 0; mi < 4; ++mi)
    #pragma unroll
    for (int ni = 0; ni < 4; ++ni)
      #pragma unroll
      for (int j = 0; j < 4; ++j) {
        const float e = __expf(INV_T_EFF * acc[mi][ni][j]);
        rsum[mi][j] += e;
        csum[ni]    += e;
      }

  #pragma unroll
  for (int mi = 0; mi < 4; ++mi) {
    #pragma unroll
    for (int off = 1; off < 16; off <<= 1)
      #pragma unroll
      for (int j = 0; j < 4; ++j) rsum[mi][j] += __shfl_xor(rsum[mi][j], off, 64);
    if ((l & 15) == 0) {
      const int rloc = wr * 64 + mi * 16 + s4 * 4;
      #pragma unroll
      for (int j = 0; j < 4; ++j) rowbuf[wc * TILE + rloc + j] = rsum[mi][j];
    }
  }
  #pragma unroll
  for (int off = 16; off < 64; off <<= 1)
    #pragma unroll
    for (int ni = 0; ni < 4; ++ni) csum[ni] += __shfl_xor(csum[ni], off, 64);
  if (l < 16) {
    #pragma unroll
    for (int ni = 0; ni < 4; ++ni)
      colbuf[wr * TILE + wc * 64 + ni * 16 + l] = csum[ni];
  }
  __syncthreads();

  if (t < TILE) {
    S_partial[(long)J * TWO_N + rI + t] = rowbuf[t] + rowbuf[TILE + t];
  } else if (I != J) {
    const int c = t - TILE;
    S_partial[(long)I * TWO_N + cJ + c] = colbuf[c] + colbuf[TILE + c];
  }
}

// ---------------- kernel 3: per-row log(denominator) + inline exp_ik sum ---
__global__ __launch_bounds__(256) void rowlog_kernel(
    const float* __restrict__ S_partial, const float* __restrict__ diagexp,
    const float* __restrict__ exp_ik, float* __restrict__ blockpart)
{
  const int t = threadIdx.x;
  const int r = blockIdx.x * 256 + t;

  float fu[1] = {0.f};
  #pragma unroll 4
  for (int i = t; i < N_ROWS; i += 256) fu[0] += exp_ik[i];
  block_reduce_bcast<1>(fu);
  const float denom_fu = 2.0f * fu[0];

  float s = 0.f;
  #pragma unroll 8
  for (int Jb = 0; Jb < NJB; ++Jb) s += S_partial[(long)Jb * TWO_N + r];
  float v[1];
  v[0] = logf(s - diagexp[r] + denom_fu);
  block_reduce_bcast<1>(v);
  if (t == 0) blockpart[blockIdx.x] = v[0];
}

// ---------------- kernel 4: final scalar (+ inline pos_ij sum) -------------
__global__ __launch_bounds__(256) void final_kernel(
    const float* __restrict__ blockpart, const float* __restrict__ pos_ij,
    float* __restrict__ out)
{
  const int t = threadIdx.x;   // 256 threads
  float v[2] = {0.f, 0.f};
  #pragma unroll 4
  for (int i = t; i < N_ROWS; i += 256) v[0] += pos_ij[i];
  if (t < TWO_N / 256) v[1] = blockpart[t];
  block_reduce_bcast<2>(v);
  if (t == 0) out[0] = (v[1] - 10.0f * v[0]) / (float)TWO_N;
}

extern "C" void kernel_launch(void* const* d_in, const int* in_sizes, int n_in,
                              void* d_out, int out_size, void* d_ws, size_t ws_size,
                              hipStream_t stream)
{
  const float* ei = (const float*)d_in[0];
  const float* ej = (const float*)d_in[1];
  const float* ek = (const float*)d_in[2];
  float* out = (float*)d_out;

  char* ws = (char*)d_ws;
  unsigned char* rep4 = (unsigned char*)ws;                            // 2 MB
  float* S_partial = (float*)(ws + 2u * 1024 * 1024);                  // 2 MB
  float* diagexp   = (float*)(ws + 4u * 1024 * 1024);                  // 32 KB
  float* pos_ij    = (float*)(ws + 4u * 1024 * 1024 + 32 * 1024);      // 16 KB
  float* exp_ik    = (float*)(ws + 4u * 1024 * 1024 + 48 * 1024);      // 16 KB
  float* blockpart = (float*)(ws + 4u * 1024 * 1024 + 64 * 1024);      // 128 B

  normalize_kernel<<<N_ROWS / 4, 256, 0, stream>>>(ei, ej, ek, rep4, diagexp,
                                                   pos_ij, exp_ik);
  gemm_expsum_kernel<<<NPAIRS, 256, 0, stream>>>(rep4, S_partial);
  rowlog_kernel<<<TWO_N / 256, 256, 0, stream>>>(S_partial, diagexp, exp_ik,
                                                 blockpart);
  final_kernel<<<1, 256, 0, stream>>>(blockpart, pos_ij, out);
}